// Round 4
// baseline (770.913 us; speedup 1.0000x reference)
//
#include <hip/hip_runtime.h>
#include <stdint.h>

typedef __bf16 bf16x8 __attribute__((ext_vector_type(8)));
typedef float f32x4 __attribute__((ext_vector_type(4)));

#define AS1C(p) ((const __attribute__((address_space(1))) void*)(p))
#define AS3(p)  ((__attribute__((address_space(3))) void*)(p))

__device__ __forceinline__ unsigned short f2bf(float f) {
    unsigned int u = __float_as_uint(f);
    u += 0x7FFFu + ((u >> 16) & 1u);   // round-to-nearest-even
    return (unsigned short)(u >> 16);
}
__device__ __forceinline__ float leaky(float v) { return v > 0.0f ? v : 0.01f * v; }
// Involution swizzles (bits 4-6 ^= higher bits, disjoint => self-inverse).
// swz7: applied to full byte offset of staged tiles; same XOR on stage-source and read.
// swz8: for h [128][128] bf16 (row stride 256B).
__device__ __forceinline__ int swz7(int d) { return d ^ (((d >> 7) & 7) << 4); }
__device__ __forceinline__ int swz8(int d) { return d ^ (((d >> 8) & 7) << 4); }

// ---------------- weight convert + transpose: in[K][N] f32 -> out[N][K] bf16 --------
__global__ void k_transpose_bf16(const float* __restrict__ in, unsigned short* __restrict__ out,
                                 int K, int N) {
    int idx = blockIdx.x * 256 + threadIdx.x;
    if (idx >= K * N) return;
    int n = idx / K;
    int k = idx - n * K;
    out[idx] = f2bf(in[(size_t)k * N + n]);
}

struct KParams {
    const float* src_xy; const float* dst_xy; const float* time_s;
    const float* wait_src; const float* wait_dst;
    const float* sp[8]; const float* dp[8];
    const float* t_w; const float* t_b; const float* ws_w; const float* ws_b;
    const float* wd_w; const float* wd_b;
    const float* b1; const float* b2;
    const unsigned short* W1T; const unsigned short* W2T;
    float* out;
};

// LDS map (bytes)
#define OF_SCAL 0        // 7*128*4    = 3584  row scalars
#define OF_PAR  3584     // 14*128*4   = 7168  encoder w/b per k-chunk
#define OF_F    10752    // 2 * 16384  feats [128][64] bf16, dbuf
#define OF_W    43520    // 65536: W1 chunks 2x16384 OR W2 chunks 2x32768
#define OF_H    109056   // 32768: h chunk [128][128] bf16
#define LDS_TOT 141824

// Fused: encode -> h = leaky(F@W1+b1) (per 128-col chunk, in LDS) -> out += h@W2chunk -> leaky(+b2)
__launch_bounds__(512, 2)
__global__ void k_fused(KParams p) {
    extern __shared__ char sm[];
    float* scal = (float*)(sm + OF_SCAL);
    float* par  = (float*)(sm + OF_PAR);

    const int tid  = threadIdx.x;
    const int lane = tid & 63, wid = tid >> 6;
    const int lrow = lane & 15, kg = lane >> 4;
    const int wr1 = wid >> 1, wc1 = wid & 1;   // GEMM1: 4M x 2N waves (wave tile 32x64)
    const int wr2 = wid >> 2, wc2 = wid & 3;   // GEMM2: 2M x 4N waves (wave tile 64x128)

    // XCD swizzle (grid = 1024, % 8 == 0 -> simple bijective form)
    int swzb = (blockIdx.x & 7) * ((int)gridDim.x >> 3) + ((int)blockIdx.x >> 3);
    const size_t brow = (size_t)swzb * 128;

    // ---- preload per-row scalars: scal[f][r], f: sx,sy,dx,dy,t,ws,wd ----
    for (int j = tid; j < 896; j += 512) {      // grid-stride: block has 512 threads, 896 entries
        int f = j >> 7, r = j & 127;
        size_t gr = brow + r;
        float v;
        if      (f == 0) v = p.src_xy[2 * gr];
        else if (f == 1) v = p.src_xy[2 * gr + 1];
        else if (f == 2) v = p.dst_xy[2 * gr];
        else if (f == 3) v = p.dst_xy[2 * gr + 1];
        else if (f == 4) v = p.time_s[gr];
        else if (f == 5) v = p.wait_src[gr];
        else             v = p.wait_dst[gr];
        scal[f * 128 + r] = v;
    }
    // ---- preload encoder params: par[kt][isb][c] (kt 0..13, w then b, 64 each) ----
    for (int j = tid; j < 1792; j += 512) {
        int kt = j >> 7, rem = j & 127, isb = (rem >> 6) & 1, c = rem & 63;
        float v;
        if (kt < 8) {
            const float* const* arr = (kt < 4) ? p.sp : p.dp;
            v = arr[(kt & 3) * 2 + isb][c];
        } else {
            int which = (kt - 8) >> 1;
            const float* q = (which == 0) ? (isb ? p.t_b : p.t_w)
                           : (which == 1) ? (isb ? p.ws_b : p.ws_w)
                                          : (isb ? p.wd_b : p.wd_w);
            v = q[((kt & 1) << 6) + c];
        }
        par[j] = v;
    }

    f32x4 oacc[4][8] = {};   // out tile: wave 64x128 -> 4m x 8n frags
    __syncthreads();

    // encode one feats k-chunk [128][64] bf16 into dst (swz7 layout).
    // global col = ke*64 + c; each chunk is a single (scalar, op, w/b) segment.
    auto encode = [&](int ke, char* dst) {
        int r = tid >> 2, c0 = (tid & 3) << 4;
        int sidx = (ke < 8) ? (((ke >> 2) << 1) + ((ke >> 1) & 1)) : (4 + ((ke - 8) >> 1));
        float s = scal[sidx * 128 + r];
        const float* wv = par + ke * 128;
        const float* bv = wv + 64;
        float val[16];
        if (ke < 8) {
            if (ke & 1) {
#pragma unroll
                for (int i = 0; i < 16; ++i) val[i] = __cosf(fmaf(s, wv[c0 + i], bv[c0 + i]));
            } else {
#pragma unroll
                for (int i = 0; i < 16; ++i) val[i] = __sinf(fmaf(s, wv[c0 + i], bv[c0 + i]));
            }
        } else {
#pragma unroll
            for (int i = 0; i < 16; ++i) val[i] = leaky(fmaf(s, wv[c0 + i], bv[c0 + i]));
        }
        uint4 pk0, pk1;
        pk0.x = (unsigned)f2bf(val[0])  | ((unsigned)f2bf(val[1])  << 16);
        pk0.y = (unsigned)f2bf(val[2])  | ((unsigned)f2bf(val[3])  << 16);
        pk0.z = (unsigned)f2bf(val[4])  | ((unsigned)f2bf(val[5])  << 16);
        pk0.w = (unsigned)f2bf(val[6])  | ((unsigned)f2bf(val[7])  << 16);
        pk1.x = (unsigned)f2bf(val[8])  | ((unsigned)f2bf(val[9])  << 16);
        pk1.y = (unsigned)f2bf(val[10]) | ((unsigned)f2bf(val[11]) << 16);
        pk1.z = (unsigned)f2bf(val[12]) | ((unsigned)f2bf(val[13]) << 16);
        pk1.w = (unsigned)f2bf(val[14]) | ((unsigned)f2bf(val[15]) << 16);
        int d = r * 128 + c0 * 2;
        *(uint4*)(dst + swz7(d))      = pk0;
        *(uint4*)(dst + swz7(d + 16)) = pk1;
    };
    // Stage W1T chunk [128 outcols][64 k] bf16 (16KB): linear LDS dest, swz7'd source.
    auto stageW1 = [&](int nc, int kt) {
        char* dst = sm + OF_W + (kt & 1) * 16384;
#pragma unroll
        for (int j = 0; j < 2; ++j) {
            int d = tid * 16 + j * 8192;
            int ds = swz7(d);
            int r = ds >> 7, cb = ds & 127;
            const unsigned short* src = p.W1T + (size_t)(nc * 128 + r) * 896 + kt * 64 + (cb >> 1);
            __builtin_amdgcn_global_load_lds(AS1C(src), AS3(dst + d), 16, 0, 0);
        }
    };
    // Stage W2T chunk [512 outcols][32 k] bf16 (32KB).
    auto stageW2 = [&](int nc, int k2) {
        char* dst = sm + OF_W + (k2 & 1) * 32768;
#pragma unroll
        for (int j = 0; j < 4; ++j) {
            int d = tid * 16 + j * 8192;
            int ds = swz7(d);
            int r = ds >> 6, cb = ds & 63;
            const unsigned short* src = p.W2T + (size_t)r * 512 + nc * 128 + k2 * 32 + (cb >> 1);
            __builtin_amdgcn_global_load_lds(AS1C(src), AS3(dst + d), 16, 0, 0);
        }
    };

    for (int nc = 0; nc < 4; ++nc) {
        // ---- GEMM1: h-chunk[128][128] = feats[128][896] @ W1T[nc*128..+128][896]^T ----
        stageW1(nc, 0);
        encode(0, sm + OF_F);
        f32x4 hacc[2][4] = {};
        __syncthreads();
        for (int kt = 0; kt < 14; ++kt) {
            char* fb = sm + OF_F + (kt & 1) * 16384;
            char* wb = sm + OF_W + (kt & 1) * 16384;
            if (kt < 13) {
                stageW1(nc, kt + 1);                                  // prefetch next W1 chunk
                encode(kt + 1, sm + OF_F + ((kt + 1) & 1) * 16384);   // compute next feats chunk
            }
#pragma unroll
            for (int kk = 0; kk < 2; ++kk) {
                bf16x8 af[2], bfr[4];
#pragma unroll
                for (int m = 0; m < 2; ++m)
                    af[m] = *(const bf16x8*)(fb + swz7((wr1 * 32 + m * 16 + lrow) * 128 + kk * 64 + kg * 16));
#pragma unroll
                for (int n = 0; n < 4; ++n)
                    bfr[n] = *(const bf16x8*)(wb + swz7((wc1 * 64 + n * 16 + lrow) * 128 + kk * 64 + kg * 16));
#pragma unroll
                for (int m = 0; m < 2; ++m)
#pragma unroll
                    for (int n = 0; n < 4; ++n)
                        hacc[m][n] = __builtin_amdgcn_mfma_f32_16x16x32_bf16(af[m], bfr[n], hacc[m][n], 0, 0, 0);
            }
            __syncthreads();
        }
        // prefetch first W2 chunk while writing h
        stageW2(nc, 0);
        {
            float b1v[4];
#pragma unroll
            for (int n = 0; n < 4; ++n) b1v[n] = p.b1[nc * 128 + wc1 * 64 + n * 16 + lrow];
#pragma unroll
            for (int m = 0; m < 2; ++m)
#pragma unroll
                for (int n = 0; n < 4; ++n)
#pragma unroll
                    for (int rg = 0; rg < 4; ++rg) {
                        int hr = wr1 * 32 + m * 16 + kg * 4 + rg;   // C/D: row=(lane>>4)*4+reg
                        int hc = wc1 * 64 + n * 16 + lrow;          //      col=lane&15
                        *(unsigned short*)(sm + OF_H + swz8(hr * 256 + hc * 2)) =
                            f2bf(leaky(hacc[m][n][rg] + b1v[n]));
                    }
        }
        __syncthreads();
        // ---- GEMM2 partial-k: oacc += h-chunk @ W2T[:, nc*128..+128]^T ----
        for (int k2 = 0; k2 < 4; ++k2) {
            char* wb = sm + OF_W + (k2 & 1) * 32768;
            if (k2 < 3) stageW2(nc, k2 + 1);
            bf16x8 ha[4], wfr[8];
#pragma unroll
            for (int m = 0; m < 4; ++m)
                ha[m] = *(const bf16x8*)(sm + OF_H + swz8((wr2 * 64 + m * 16 + lrow) * 256 + k2 * 64 + kg * 16));
#pragma unroll
            for (int n = 0; n < 8; ++n)
                wfr[n] = *(const bf16x8*)(wb + swz7((wc2 * 128 + n * 16 + lrow) * 64 + kg * 16));
#pragma unroll
            for (int m = 0; m < 4; ++m)
#pragma unroll
                for (int n = 0; n < 8; ++n)
                    oacc[m][n] = __builtin_amdgcn_mfma_f32_16x16x32_bf16(ha[m], wfr[n], oacc[m][n], 0, 0, 0);
            __syncthreads();
        }
    }
    // ---- epilogue: out = leaky(oacc + b2), fp32 ----
#pragma unroll
    for (int n = 0; n < 8; ++n) {
        int col = wc2 * 128 + n * 16 + lrow;
        float b2v = p.b2[col];
#pragma unroll
        for (int m = 0; m < 4; ++m) {
            size_t row0 = brow + wr2 * 64 + m * 16 + kg * 4;
#pragma unroll
            for (int rg = 0; rg < 4; ++rg)
                p.out[(row0 + rg) * 512 + col] = leaky(oacc[m][n][rg] + b2v);
        }
    }
}

extern "C" void kernel_launch(void* const* d_in, const int* in_sizes, int n_in,
                              void* d_out, int out_size, void* d_ws, size_t ws_size,
                              hipStream_t stream) {
    KParams kp;
    kp.src_xy   = (const float*)d_in[0];
    kp.dst_xy   = (const float*)d_in[1];
    kp.time_s   = (const float*)d_in[2];
    kp.wait_src = (const float*)d_in[3];
    kp.wait_dst = (const float*)d_in[4];
    for (int i = 0; i < 8; ++i) kp.sp[i] = (const float*)d_in[5 + i];
    for (int i = 0; i < 8; ++i) kp.dp[i] = (const float*)d_in[13 + i];
    kp.t_w  = (const float*)d_in[21];
    kp.t_b  = (const float*)d_in[22];
    kp.ws_w = (const float*)d_in[23];
    kp.ws_b = (const float*)d_in[24];
    kp.wd_w = (const float*)d_in[25];
    kp.wd_b = (const float*)d_in[26];
    const float* W1 = (const float*)d_in[27];
    kp.b1 = (const float*)d_in[28];
    const float* W2 = (const float*)d_in[29];
    kp.b2 = (const float*)d_in[30];
    kp.out = (float*)d_out;

    unsigned short* W1T = (unsigned short*)d_ws;                       // 512*896 bf16
    unsigned short* W2T = (unsigned short*)((char*)d_ws + 917504);     // 512*512 bf16
    kp.W1T = W1T;
    kp.W2T = W2T;

    k_transpose_bf16<<<(896 * 512 + 255) / 256, 256, 0, stream>>>(W1, W1T, 896, 512);
    k_transpose_bf16<<<(512 * 512 + 255) / 256, 256, 0, stream>>>(W2, W2T, 512, 512);

    hipFuncSetAttribute((const void*)k_fused,
                        hipFuncAttributeMaxDynamicSharedMemorySize, LDS_TOT);
    k_fused<<<1024, 512, LDS_TOT, stream>>>(kp);
}